// Round 7
// baseline (278.334 us; speedup 1.0000x reference)
//
#include <hip/hip_runtime.h>
#include <hip/hip_bf16.h>

#define NB 2
#define L_SEQ 2048
#define NH 16
#define DKH 64
#define DMODEL 1024
#define MROWS (NB * L_SEQ)          // 4096
#define QSCALE 0.18033688f          // 0.125 * log2(e), folded into Q
#define DD (DMODEL * DMODEL)

typedef __attribute__((ext_vector_type(8))) short short8;
typedef __attribute__((ext_vector_type(4))) float f32x4;

static __device__ __forceinline__ unsigned short f2bf(float f) {
    unsigned u = __float_as_uint(f);
    u += 0x7fffu + ((u >> 16) & 1u);   // RTN-even
    return (unsigned short)(u >> 16);
}

static __device__ __forceinline__ float fexp2(float x) {
#if __has_builtin(__builtin_amdgcn_exp2f)
    return __builtin_amdgcn_exp2f(x);
#else
    return __expf(x * 0.6931471806f);
#endif
}

static __device__ __forceinline__ unsigned pk_bf16(float a, float b) {
    __hip_bfloat162 h = __float22bfloat162_rn(make_float2(a, b));
    return *reinterpret_cast<unsigned*>(&h);
}

static __device__ __forceinline__ void gll16(const void* g, void* l) {
    __builtin_amdgcn_global_load_lds(
        (const __attribute__((address_space(1))) void*)g,
        (__attribute__((address_space(3))) void*)l, 16, 0, 0);
}

// ---------------------------------------------------------------------------
// prep: fused cast3 + castWt + maskbits (unchanged from round 6)
// ---------------------------------------------------------------------------
__global__ __launch_bounds__(256)
void prep(const float* __restrict__ Xq, const float* __restrict__ Xk,
          const float* __restrict__ Xv, const float* __restrict__ w0,
          const float* __restrict__ w1, const float* __restrict__ w2,
          const float* __restrict__ w3, const int* __restrict__ mask,
          unsigned short* __restrict__ XB, unsigned short* __restrict__ WtB,
          unsigned long long* __restrict__ MWT)
{
    __shared__ float ts[32][33];
    const int bx = blockIdx.x;
    const int t  = threadIdx.x;

    if (bx < 12288) {
        const int z = bx >> 12;
        const float* src = (z == 0) ? Xq : (z == 1) ? Xk : Xv;
        const size_t i4 = (size_t)(bx & 4095) * 256 + t;
        float4 v = ((const float4*)src)[i4];
        ushort4 o;
        o.x = f2bf(v.x); o.y = f2bf(v.y); o.z = f2bf(v.z); o.w = f2bf(v.w);
        ((ushort4*)(XB + (size_t)z * 4194304))[i4] = o;
    } else if (bx < 16384) {
        const int idx = bx - 12288;
        const int z   = idx >> 10;
        const int rem = idx & 1023;
        const float* W = (z == 0) ? w0 : (z == 1) ? w1 : (z == 2) ? w2 : w3;
        unsigned short* Wt = WtB + (size_t)z * DD;
        const int n0 = (rem & 31) * 32;
        const int k0 = (rem >> 5) * 32;
        const int r  = t >> 3;
        const int c  = (t & 7) * 4;
        float4 v = *(const float4*)&W[(size_t)(k0 + r) * DMODEL + n0 + c];
        ts[r][c + 0] = v.x; ts[r][c + 1] = v.y;
        ts[r][c + 2] = v.z; ts[r][c + 3] = v.w;
        __syncthreads();
        ushort4 o;
        o.x = f2bf(ts[c + 0][r]); o.y = f2bf(ts[c + 1][r]);
        o.z = f2bf(ts[c + 2][r]); o.w = f2bf(ts[c + 3][r]);
        *(ushort4*)&Wt[(size_t)(n0 + r) * DMODEL + k0 + c] = o;
    } else {
        const int lane = t & 63;
        const size_t wid = (size_t)(bx - 16384) * 4 + (t >> 6);
        const int mv = mask[wid * 64 + lane];
        const unsigned long long bits = __ballot(mv != 0);
        if (lane == 0) {
            const int b   = (int)(wid >> 16);
            const int rem = (int)(wid & 65535);
            const int row = rem >> 5;
            const int wd  = rem & 31;
            MWT[((size_t)b * 32 + wd) * L_SEQ + row] = bits;
        }
    }
}

// ---------------------------------------------------------------------------
// QKV GEMM (unchanged from round 6): BK=32 dbuf, one barrier/iter.
// ---------------------------------------------------------------------------
__global__ __launch_bounds__(256)
void gemm_qkv(const unsigned short* __restrict__ XB,
              const unsigned short* __restrict__ WtB,
              unsigned short* __restrict__ QKV)
{
    __shared__ __align__(16) unsigned short SMEM[16384];   // 32 KB

    const int t    = threadIdx.x;
    const int w    = t >> 6;
    const int lane = t & 63;
    const int z    = blockIdx.z;
    const int m0   = blockIdx.y * 128;
    const int n0   = blockIdx.x * 128;

    const unsigned short* A = XB  + (size_t)z * ((size_t)MROWS * DMODEL);
    const unsigned short* B = WtB + (size_t)z * DD;

    const int srow = lane >> 2;
    const int sc4  = (lane & 3) ^ (srow & 3);

    const unsigned short* ag[2];
    const unsigned short* bg[2];
    int lao[2], lbo[2];
#pragma unroll
    for (int g = 0; g < 2; ++g) {
        const int R = w * 32 + g * 16;
        ag[g] = A + (size_t)(m0 + R + srow) * DMODEL + sc4 * 8;
        bg[g] = B + (size_t)(n0 + R + srow) * DMODEL + sc4 * 8;
        lao[g] = R * 32;
        lbo[g] = R * 32;
    }

    const int ml = lane & 15;
    const int q  = lane >> 4;
    const int wm = (w >> 1) * 64;
    const int wn = (w & 1) * 64;

    const f32x4 z4 = {0.f, 0.f, 0.f, 0.f};
    f32x4 acc[4][4];
#pragma unroll
    for (int i = 0; i < 4; ++i)
#pragma unroll
        for (int j = 0; j < 4; ++j) acc[i][j] = z4;

#pragma unroll
    for (int g = 0; g < 2; ++g) {
        gll16(ag[g], &SMEM[lao[g]]);
        gll16(bg[g], &SMEM[8192 + lbo[g]]);
    }

    for (int j = 0; j < 32; ++j) {
        const int cur = j & 1;
        __syncthreads();
        if (j < 31) {
            const int kt = (j + 1) * 32;
            const int nb = (cur ^ 1) * 4096;
#pragma unroll
            for (int g = 0; g < 2; ++g) {
                gll16(ag[g] + kt, &SMEM[nb + lao[g]]);
                gll16(bg[g] + kt, &SMEM[8192 + nb + lbo[g]]);
            }
        }
        const unsigned short* As = &SMEM[cur * 4096];
        const unsigned short* Bs = &SMEM[8192 + cur * 4096];
        short8 av[4], bv[4];
#pragma unroll
        for (int mt = 0; mt < 4; ++mt)
            av[mt] = *(const short8*)
                &As[(wm + mt * 16 + ml) * 32 + ((q ^ (ml & 3)) * 8)];
#pragma unroll
        for (int nt = 0; nt < 4; ++nt)
            bv[nt] = *(const short8*)
                &Bs[(wn + nt * 16 + ml) * 32 + ((q ^ (ml & 3)) * 8)];
#pragma unroll
        for (int mt = 0; mt < 4; ++mt)
#pragma unroll
            for (int nt = 0; nt < 4; ++nt)
                acc[mt][nt] = __builtin_amdgcn_mfma_f32_16x16x32_bf16(
                    av[mt], bv[nt], acc[mt][nt], 0, 0, 0);
    }

    unsigned short* O = QKV + (size_t)z * ((size_t)MROWS * DMODEL);
    if (z == 2) {
        __syncthreads();
        unsigned short* Ts = SMEM;
#pragma unroll
        for (int mt = 0; mt < 4; ++mt) {
            const int trow0 = wm + mt * 16 + q * 4;
            const int ch    = trow0 >> 3;
#pragma unroll
            for (int nt = 0; nt < 4; ++nt) {
                const int tcol = wn + nt * 16 + ml;
                const int pc   = (ch & 8) | ((ch & 7) ^ (tcol & 7));
                ushort4 pv;
                pv.x = f2bf(acc[mt][nt][0]); pv.y = f2bf(acc[mt][nt][1]);
                pv.z = f2bf(acc[mt][nt][2]); pv.w = f2bf(acc[mt][nt][3]);
                *(ushort4*)&Ts[tcol * 128 + pc * 8 + (trow0 & 7)] = pv;
            }
        }
        __syncthreads();
        const int bb = m0 >> 11;
        const int l0 = (m0 & (L_SEQ - 1)) + (t & 15) * 8;
        const int cr = t & 15;
#pragma unroll
        for (int it = 0; it < 8; ++it) {
            const int tcol = (t >> 4) + 16 * it;
            const int pc   = (cr & 8) | ((cr & 7) ^ (tcol & 7));
            short8 vv = *(const short8*)&Ts[tcol * 128 + pc * 8];
            const int n  = n0 + tcol;
            const int hh = n >> 6;
            const int dk = n & (DKH - 1);
            *(short8*)&O[((size_t)(bb * NH + hh) * DKH + dk) * L_SEQ + l0] = vv;
        }
    } else {
        const float qs = (z == 0) ? QSCALE : 1.0f;
#pragma unroll
        for (int mt = 0; mt < 4; ++mt) {
            const int gr0 = m0 + wm + mt * 16 + q * 4;
#pragma unroll
            for (int nt = 0; nt < 4; ++nt) {
                const int col = n0 + wn + nt * 16 + ml;
                const int hh  = col >> 6;
                const int dk  = col & (DKH - 1);
#pragma unroll
                for (int r = 0; r < 4; ++r) {
                    const int row = gr0 + r;
                    const int bb  = row >> 11;
                    const int l   = row & (L_SEQ - 1);
                    O[(((size_t)(bb * NH + hh) * L_SEQ + l) << 6) + dk] =
                        f2bf(acc[mt][nt][r] * qs);
                }
            }
        }
    }
}

// ---------------------------------------------------------------------------
// Output GEMM (unchanged from round 6)
// ---------------------------------------------------------------------------
__global__ __launch_bounds__(256)
void gemm_out(const unsigned short* __restrict__ OB,
              const unsigned short* __restrict__ Wt,
              float* __restrict__ out)
{
    __shared__ __align__(16) unsigned short As[2][2048];
    __shared__ __align__(16) unsigned short Bs[2][4096];

    const int t    = threadIdx.x;
    const int w    = t >> 6;
    const int lane = t & 63;
    const int m0   = blockIdx.y * 64;
    const int n0   = blockIdx.x * 128;

    const int srow = lane >> 2;
    const int sc4  = (lane & 3) ^ (srow & 3);

    const unsigned short* ag =
        OB + (size_t)(m0 + w * 16 + srow) * DMODEL + sc4 * 8;
    const unsigned short* bg[2];
    int lbo[2];
#pragma unroll
    for (int g = 0; g < 2; ++g) {
        const int R = w * 32 + g * 16;
        bg[g] = Wt + (size_t)(n0 + R + srow) * DMODEL + sc4 * 8;
        lbo[g] = R * 32;
    }
    const int lao = (w * 16) * 32;

    const int ml = lane & 15;
    const int q  = lane >> 4;
    const int wm = (w >> 1) * 32;
    const int wn = (w & 1) * 64;

    const f32x4 z4 = {0.f, 0.f, 0.f, 0.f};
    f32x4 acc[2][4];
#pragma unroll
    for (int i = 0; i < 2; ++i)
#pragma unroll
        for (int j = 0; j < 4; ++j) acc[i][j] = z4;

    gll16(ag, &As[0][lao]);
#pragma unroll
    for (int g = 0; g < 2; ++g) gll16(bg[g], &Bs[0][lbo[g]]);

    for (int j = 0; j < 32; ++j) {
        const int cur = j & 1;
        __syncthreads();
        if (j < 31) {
            const int kt = (j + 1) * 32;
            gll16(ag + kt, &As[cur ^ 1][lao]);
#pragma unroll
            for (int g = 0; g < 2; ++g)
                gll16(bg[g] + kt, &Bs[cur ^ 1][lbo[g]]);
        }
        short8 av[2], bv[4];
#pragma unroll
        for (int mt = 0; mt < 2; ++mt)
            av[mt] = *(const short8*)
                &As[cur][(wm + mt * 16 + ml) * 32 + ((q ^ (ml & 3)) * 8)];
#pragma unroll
        for (int nt = 0; nt < 4; ++nt)
            bv[nt] = *(const short8*)
                &Bs[cur][(wn + nt * 16 + ml) * 32 + ((q ^ (ml & 3)) * 8)];
#pragma unroll
        for (int mt = 0; mt < 2; ++mt)
#pragma unroll
            for (int nt = 0; nt < 4; ++nt)
                acc[mt][nt] = __builtin_amdgcn_mfma_f32_16x16x32_bf16(
                    av[mt], bv[nt], acc[mt][nt], 0, 0, 0);
    }

#pragma unroll
    for (int mt = 0; mt < 2; ++mt) {
        const int gr0 = m0 + wm + mt * 16 + q * 4;
#pragma unroll
        for (int nt = 0; nt < 4; ++nt) {
            const int col = n0 + wn + nt * 16 + ml;
#pragma unroll
            for (int r = 0; r < 4; ++r)
                out[(size_t)(gr0 + r) * DMODEL + col] = acc[mt][nt][r];
        }
    }
}

// ---------------------------------------------------------------------------
// MFMA flash attention, K-SPLIT: 512 threads = 8 waves = 4 q-subtiles x
// 2 k-halves. Each iter stages k=128 of K and V^T; wave (qsub,ksub) computes
// its 64-k strip -> 8192 total waves = 32 waves/CU (2x round 6) so the
// serial per-iter chain (S-MFMA -> exp -> P roundtrip -> PV) of one wave
// overlaps with 7 phase-shifted others per SIMD. LDS 40 KB = 4 blocks/CU.
// P staged per 32-k half (in-place reuse, WAR handled by per-wave lgkmcnt).
// Epilogue reduces the two k-halves through LDS (reuses K tile area).
// Zero-fill mask semantics: p = exp2(s*bit), Q pre-scaled by 0.125*log2e.
// ---------------------------------------------------------------------------
__global__ __launch_bounds__(512, 6)
void attn_mfma(const unsigned short* __restrict__ Qb,
               const unsigned short* __restrict__ Kb,
               const unsigned short* __restrict__ Vtb,
               const unsigned long long* __restrict__ MWT,
               unsigned short* __restrict__ OB)
{
    __shared__ __align__(16) unsigned short Ks[128 * 64];   // 16 KB [k][d]
    __shared__ __align__(16) unsigned short Vts[64 * 128];  // 16 KB [d][k]
    __shared__ __align__(16) unsigned short Ps[8][512];     //  8 KB [16q][32k]/wave

    const int t    = threadIdx.x;
    const int w    = t >> 6;          // 0..7
    const int qsub = w & 3;
    const int ksub = w >> 2;          // 0..1
    const int lane = t & 63;
    const int ml   = lane & 15;
    const int quad = lane >> 4;

    // XCD-aware decode: (b,h) pair pinned to one XCD
    const int bid = blockIdx.x;
    const int p   = (bid >> 8) * 8 + (bid & 7);
    const int jq  = (bid >> 3) & 31;
    const int h   = p & 15;
    const int b   = p >> 4;
    const int q0  = jq * 64;

    const size_t hoff = (size_t)(b * NH + h) * L_SEQ * DKH;
    const unsigned short* Qh  = Qb  + hoff;
    const unsigned short* Kh  = Kb  + hoff;
    const unsigned short* Vth = Vtb + hoff;     // [64][L_SEQ]

    // Q fragments direct from global (loop-invariant); q-row = q0+qsub*16+ml
    short8 qf[2];
#pragma unroll
    for (int s = 0; s < 2; ++s)
        qf[s] = *(const short8*)
            &Qh[(size_t)(q0 + qsub * 16 + ml) * DKH + (s * 4 + quad) * 8];

    // K staging: wave stages k-rows w*16..+15 (2 gll16, 8 rows each)
    const int kr8 = lane >> 3;                     // 0..7
    const int kc  = (lane & 7) ^ kr8;              // logical chunk
    const unsigned short* kgp[2];
    int lko[2];
#pragma unroll
    for (int g = 0; g < 2; ++g) {
        const int R0 = w * 16 + g * 8;
        kgp[g] = Kh + (size_t)(R0 + kr8) * DKH + kc * 8;
        lko[g] = R0 * 64;
    }
    // V^T staging: wave stages d-rows w*8..+7 (2 gll16, 4 rows x 16 chunks)
    const int vr4 = lane >> 4;                     // 0..3
    const int vpc = lane & 15;
    const unsigned short* vgp[2];
    int lvo[2];
#pragma unroll
    for (int g = 0; g < 2; ++g) {
        const int D0 = w * 8 + g * 4;
        const int vc = (vpc & 8) | ((vpc & 7) ^ ((g * 4 + vr4) & 7));
        vgp[g] = Vth + (size_t)(D0 + vr4) * L_SEQ + vc * 8;
        lvo[g] = D0 * 128;
    }

    // mask: lanes<16 hold word for q-row qsub*16+lane; word idx = 2j+ksub
    const unsigned long long* mg =
        MWT + ((size_t)b * 32 + ksub) * L_SEQ + q0 + qsub * 16;
    unsigned long long mcur = 0, mnxt = 0;
    if (lane < 16) mcur = mg[lane];

    f32x4 oacc[4];
    const f32x4 z4 = {0.f, 0.f, 0.f, 0.f};
#pragma unroll
    for (int dt = 0; dt < 4; ++dt) oacc[dt] = z4;
    float l_i = 0.f;

    for (int j = 0; j < 16; ++j) {
        __syncthreads();                 // prev iter's tile reads done
#pragma unroll
        for (int g = 0; g < 2; ++g) {
            gll16(kgp[g], &Ks[lko[g]]);
            gll16(vgp[g], &Vts[lvo[g]]);
            kgp[g] += 128 * DKH;         // next 128 k-rows
            vgp[g] += 128;               // next 128 cols of V^T
        }
        if (lane < 16 && j < 15)
            mnxt = mg[(size_t)(j + 1) * 2 * L_SEQ + lane];
        __syncthreads();                 // staging drained

        // ---- S^T = K @ Q^T on this wave's 64-k strip ----
        f32x4 sacc[4];
#pragma unroll
        for (int kt = 0; kt < 4; ++kt) sacc[kt] = z4;
#pragma unroll
        for (int s = 0; s < 2; ++s) {
            short8 kf[4];
#pragma unroll
            for (int kt = 0; kt < 4; ++kt)
                kf[kt] = *(const short8*)
                    &Ks[(ksub * 64 + kt * 16 + ml) * 64 +
                        (((s * 4 + quad) ^ (ml & 7)) * 8)];
#pragma unroll
            for (int kt = 0; kt < 4; ++kt)
                sacc[kt] = __builtin_amdgcn_mfma_f32_16x16x32_bf16(
                    kf[kt], qf[s], sacc[kt], 0, 0, 0);
        }

        // ---- softmax + PV, per 32-k half (P staged in-place) ----
        const unsigned long long wq = __shfl(mcur, ml) >> (quad * 4);
        float rs = 0.f;
#pragma unroll
        for (int hh2 = 0; hh2 < 2; ++hh2) {
#pragma unroll
            for (int ktp = 0; ktp < 2; ++ktp) {
                const int kt = hh2 * 2 + ktp;
                float pr[4];
#pragma unroll
                for (int r = 0; r < 4; ++r) {
                    const float mf =
                        (float)((unsigned)(wq >> (kt * 16 + r)) & 1u);
                    pr[r] = fexp2(sacc[kt][r] * mf);
                    rs += pr[r];
                }
                uint2 pk;
                pk.x = pk_bf16(pr[0], pr[1]);
                pk.y = pk_bf16(pr[2], pr[3]);
                // [16q][32k]: chunk = ktp*2 + quad>>1, pc = chunk^(ml&3)
                const int pc = (ktp * 2 + (quad >> 1)) ^ (ml & 3);
                *(uint2*)&Ps[w][ml * 32 + pc * 8 + (quad & 1) * 4] = pk;
            }
            const short8 pf = *(const short8*)
                &Ps[w][ml * 32 + ((quad ^ (ml & 3)) * 8)];
#pragma unroll
            for (int dt = 0; dt < 4; ++dt) {
                const int vcc = ksub * 8 + hh2 * 4 + quad;   // chunk 0..15
                const int vpc2 = (vcc & 8) | ((vcc & 7) ^ (ml & 7));
                const short8 vf = *(const short8*)
                    &Vts[(dt * 16 + ml) * 128 + vpc2 * 8];
                oacc[dt] = __builtin_amdgcn_mfma_f32_16x16x32_bf16(
                    vf, pf, oacc[dt], 0, 0, 0);
            }
        }
        rs += __shfl_xor(rs, 16);
        rs += __shfl_xor(rs, 32);
        l_i += rs;
        mcur = mnxt;
    }

    // ---- epilogue: reduce k-halves via LDS, normalize, store ----
    __syncthreads();                     // all K/V/P reads done
    float* Ored = (float*)Ks;            // [64 q][64 d] = 16 KB
    float* Lred = (float*)Ps;            // 64 floats
    if (ksub == 1) {
#pragma unroll
        for (int dt = 0; dt < 4; ++dt)
            *(f32x4*)&Ored[(qsub * 16 + ml) * 64 + dt * 16 + quad * 4] =
                oacc[dt];
        if (quad == 0) Lred[qsub * 16 + ml] = l_i;
    }
    __syncthreads();
    if (ksub == 0) {
        const float inv = 1.0f / (l_i + Lred[qsub * 16 + ml]);
        const int qrow = q0 + qsub * 16 + ml;
#pragma unroll
        for (int dt = 0; dt < 4; ++dt) {
            const f32x4 oh =
                *(const f32x4*)&Ored[(qsub * 16 + ml) * 64 + dt * 16 + quad * 4];
            ushort4 o4;
            o4.x = f2bf((oacc[dt][0] + oh[0]) * inv);
            o4.y = f2bf((oacc[dt][1] + oh[1]) * inv);
            o4.z = f2bf((oacc[dt][2] + oh[2]) * inv);
            o4.w = f2bf((oacc[dt][3] + oh[3]) * inv);
            *(ushort4*)&OB[(size_t)(b * L_SEQ + qrow) * DMODEL + h * DKH +
                           dt * 16 + quad * 4] = o4;
        }
    }
}

// ---------------------------------------------------------------------------
extern "C" void kernel_launch(void* const* d_in, const int* in_sizes, int n_in,
                              void* d_out, int out_size, void* d_ws, size_t ws_size,
                              hipStream_t stream)
{
    (void)in_sizes; (void)n_in; (void)out_size; (void)ws_size;

    const float* Xq   = (const float*)d_in[0];
    const float* Xk   = (const float*)d_in[1];
    const float* Xv   = (const float*)d_in[2];
    const float* Wq   = (const float*)d_in[3];
    const float* Wk   = (const float*)d_in[4];
    const float* Wv   = (const float*)d_in[5];
    const float* Wo   = (const float*)d_in[6];
    const int*   mask = (const int*)d_in[7];
    float* out = (float*)d_out;

    char* base = (char*)d_ws;
    unsigned short*     XB  = (unsigned short*)base;                 // 24 MB
    unsigned short*     WtB = (unsigned short*)(base + (24u << 20)); //  8 MB
    unsigned short*     QKV = (unsigned short*)(base + (32u << 20)); // 24 MB
    unsigned short*     OB  = (unsigned short*)(base + (56u << 20)); //  8 MB
    unsigned long long* MWT = (unsigned long long*)(base + (64u << 20)); // 1 MB

    const size_t tsz = (size_t)MROWS * DMODEL;   // 4,194,304

    prep<<<dim3(49152), 256, 0, stream>>>(
        Xq, Xk, Xv, Wq, Wk, Wv, Wo, mask, XB, WtB, MWT);

    gemm_qkv<<<dim3(8, 32, 3), 256, 0, stream>>>(XB, WtB, QKV);

    attn_mfma<<<dim3(1024), 512, 0, stream>>>(
        QKV, QKV + tsz, QKV + 2 * tsz, MWT, OB);

    gemm_out<<<dim3(8, 64), 256, 0, stream>>>(OB, WtB + 3 * (size_t)DD, out);
}

// Round 8
// 265.298 us; speedup vs baseline: 1.0491x; 1.0491x over previous
//
#include <hip/hip_runtime.h>
#include <hip/hip_bf16.h>

#define NB 2
#define L_SEQ 2048
#define NH 16
#define DKH 64
#define DMODEL 1024
#define MROWS (NB * L_SEQ)          // 4096
#define QSCALE 0.18033688f          // 0.125 * log2(e), folded into Q
#define DD (DMODEL * DMODEL)

typedef __attribute__((ext_vector_type(8))) short short8;
typedef __attribute__((ext_vector_type(4))) float f32x4;

static __device__ __forceinline__ unsigned short f2bf(float f) {
    unsigned u = __float_as_uint(f);
    u += 0x7fffu + ((u >> 16) & 1u);   // RTN-even
    return (unsigned short)(u >> 16);
}

static __device__ __forceinline__ float fexp2(float x) {
#if __has_builtin(__builtin_amdgcn_exp2f)
    return __builtin_amdgcn_exp2f(x);
#else
    return __expf(x * 0.6931471806f);
#endif
}

static __device__ __forceinline__ unsigned pk_bf16(float a, float b) {
    __hip_bfloat162 h = __float22bfloat162_rn(make_float2(a, b));
    return *reinterpret_cast<unsigned*>(&h);
}

static __device__ __forceinline__ void gll16(const void* g, void* l) {
    __builtin_amdgcn_global_load_lds(
        (const __attribute__((address_space(1))) void*)g,
        (__attribute__((address_space(3))) void*)l, 16, 0, 0);
}

// ---------------------------------------------------------------------------
// prep: fused cast3 + castWt + maskbits (unchanged)
// ---------------------------------------------------------------------------
__global__ __launch_bounds__(256)
void prep(const float* __restrict__ Xq, const float* __restrict__ Xk,
          const float* __restrict__ Xv, const float* __restrict__ w0,
          const float* __restrict__ w1, const float* __restrict__ w2,
          const float* __restrict__ w3, const int* __restrict__ mask,
          unsigned short* __restrict__ XB, unsigned short* __restrict__ WtB,
          unsigned long long* __restrict__ MWT)
{
    __shared__ float ts[32][33];
    const int bx = blockIdx.x;
    const int t  = threadIdx.x;

    if (bx < 12288) {
        const int z = bx >> 12;
        const float* src = (z == 0) ? Xq : (z == 1) ? Xk : Xv;
        const size_t i4 = (size_t)(bx & 4095) * 256 + t;
        float4 v = ((const float4*)src)[i4];
        ushort4 o;
        o.x = f2bf(v.x); o.y = f2bf(v.y); o.z = f2bf(v.z); o.w = f2bf(v.w);
        ((ushort4*)(XB + (size_t)z * 4194304))[i4] = o;
    } else if (bx < 16384) {
        const int idx = bx - 12288;
        const int z   = idx >> 10;
        const int rem = idx & 1023;
        const float* W = (z == 0) ? w0 : (z == 1) ? w1 : (z == 2) ? w2 : w3;
        unsigned short* Wt = WtB + (size_t)z * DD;
        const int n0 = (rem & 31) * 32;
        const int k0 = (rem >> 5) * 32;
        const int r  = t >> 3;
        const int c  = (t & 7) * 4;
        float4 v = *(const float4*)&W[(size_t)(k0 + r) * DMODEL + n0 + c];
        ts[r][c + 0] = v.x; ts[r][c + 1] = v.y;
        ts[r][c + 2] = v.z; ts[r][c + 3] = v.w;
        __syncthreads();
        ushort4 o;
        o.x = f2bf(ts[c + 0][r]); o.y = f2bf(ts[c + 1][r]);
        o.z = f2bf(ts[c + 2][r]); o.w = f2bf(ts[c + 3][r]);
        *(ushort4*)&Wt[(size_t)(n0 + r) * DMODEL + k0 + c] = o;
    } else {
        const int lane = t & 63;
        const size_t wid = (size_t)(bx - 16384) * 4 + (t >> 6);
        const int mv = mask[wid * 64 + lane];
        const unsigned long long bits = __ballot(mv != 0);
        if (lane == 0) {
            const int b   = (int)(wid >> 16);
            const int rem = (int)(wid & 65535);
            const int row = rem >> 5;
            const int wd  = rem & 31;
            MWT[((size_t)b * 32 + wd) * L_SEQ + row] = bits;
        }
    }
}

// ---------------------------------------------------------------------------
// QKV GEMM: BK=32 dbuf one-barrier K-loop (r6) + two fixes:
//  * XCD-pinned 1D grid: the 8 n-tiles sharing one (z,m) A-panel land on the
//    SAME XCD (bid&7 = xcd via round-robin heuristic) -> A-panel L2 reuse.
//  * Q/K epilogue via LDS restage -> short8 stores (64 lanes = 1 KB
//    contiguous per inst) instead of 64 scalar 2B scattered stores.
// ---------------------------------------------------------------------------
__global__ __launch_bounds__(256)
void gemm_qkv(const unsigned short* __restrict__ XB,
              const unsigned short* __restrict__ WtB,
              unsigned short* __restrict__ QKV)
{
    __shared__ __align__(16) unsigned short SMEM[16384];   // 32 KB

    const int t    = threadIdx.x;
    const int w    = t >> 6;
    const int lane = t & 63;

    // XCD decode: 768 blocks; xcd = bid&7; 12 (z,m) pairs per XCD, 8 n each
    const int bid   = blockIdx.x;
    const int xcd   = bid & 7;
    const int idx   = bid >> 3;           // 0..95
    const int pair  = xcd * 12 + (idx >> 3);
    const int n0    = (idx & 7) * 128;
    const int m0    = (pair & 31) * 128;
    const int z     = pair >> 5;

    const unsigned short* A = XB  + (size_t)z * ((size_t)MROWS * DMODEL);
    const unsigned short* B = WtB + (size_t)z * DD;

    const int srow = lane >> 2;
    const int sc4  = (lane & 3) ^ (srow & 3);

    const unsigned short* ag[2];
    const unsigned short* bg[2];
    int lao[2], lbo[2];
#pragma unroll
    for (int g = 0; g < 2; ++g) {
        const int R = w * 32 + g * 16;
        ag[g] = A + (size_t)(m0 + R + srow) * DMODEL + sc4 * 8;
        bg[g] = B + (size_t)(n0 + R + srow) * DMODEL + sc4 * 8;
        lao[g] = R * 32;
        lbo[g] = R * 32;
    }

    const int ml = lane & 15;
    const int q  = lane >> 4;
    const int wm = (w >> 1) * 64;
    const int wn = (w & 1) * 64;

    const f32x4 z4 = {0.f, 0.f, 0.f, 0.f};
    f32x4 acc[4][4];
#pragma unroll
    for (int i = 0; i < 4; ++i)
#pragma unroll
        for (int j = 0; j < 4; ++j) acc[i][j] = z4;

#pragma unroll
    for (int g = 0; g < 2; ++g) {
        gll16(ag[g], &SMEM[lao[g]]);
        gll16(bg[g], &SMEM[8192 + lbo[g]]);
    }

    for (int j = 0; j < 32; ++j) {
        const int cur = j & 1;
        __syncthreads();
        if (j < 31) {
            const int kt = (j + 1) * 32;
            const int nb = (cur ^ 1) * 4096;
#pragma unroll
            for (int g = 0; g < 2; ++g) {
                gll16(ag[g] + kt, &SMEM[nb + lao[g]]);
                gll16(bg[g] + kt, &SMEM[8192 + nb + lbo[g]]);
            }
        }
        const unsigned short* As = &SMEM[cur * 4096];
        const unsigned short* Bs = &SMEM[8192 + cur * 4096];
        short8 av[4], bv[4];
#pragma unroll
        for (int mt = 0; mt < 4; ++mt)
            av[mt] = *(const short8*)
                &As[(wm + mt * 16 + ml) * 32 + ((q ^ (ml & 3)) * 8)];
#pragma unroll
        for (int nt = 0; nt < 4; ++nt)
            bv[nt] = *(const short8*)
                &Bs[(wn + nt * 16 + ml) * 32 + ((q ^ (ml & 3)) * 8)];
#pragma unroll
        for (int mt = 0; mt < 4; ++mt)
#pragma unroll
            for (int nt = 0; nt < 4; ++nt)
                acc[mt][nt] = __builtin_amdgcn_mfma_f32_16x16x32_bf16(
                    av[mt], bv[nt], acc[mt][nt], 0, 0, 0);
    }

    unsigned short* O = QKV + (size_t)z * ((size_t)MROWS * DMODEL);
    __syncthreads();                     // K-loop reads done; reuse SMEM
    unsigned short* Ts = SMEM;           // [128][128] bf16 = 32 KB

    if (z == 2) {
        // V^T: stage transposed [tcol=n][trow=m] (swizzled), wide stores
#pragma unroll
        for (int mt = 0; mt < 4; ++mt) {
            const int trow0 = wm + mt * 16 + q * 4;
            const int ch    = trow0 >> 3;
#pragma unroll
            for (int nt = 0; nt < 4; ++nt) {
                const int tcol = wn + nt * 16 + ml;
                const int pc   = (ch & 8) | ((ch & 7) ^ (tcol & 7));
                ushort4 pv;
                pv.x = f2bf(acc[mt][nt][0]); pv.y = f2bf(acc[mt][nt][1]);
                pv.z = f2bf(acc[mt][nt][2]); pv.w = f2bf(acc[mt][nt][3]);
                *(ushort4*)&Ts[tcol * 128 + pc * 8 + (trow0 & 7)] = pv;
            }
        }
        __syncthreads();
        const int bb = m0 >> 11;
        const int l0 = (m0 & (L_SEQ - 1)) + (t & 15) * 8;
        const int cr = t & 15;
#pragma unroll
        for (int it = 0; it < 8; ++it) {
            const int tcol = (t >> 4) + 16 * it;
            const int pc   = (cr & 8) | ((cr & 7) ^ (tcol & 7));
            short8 vv = *(const short8*)&Ts[tcol * 128 + pc * 8];
            const int n  = n0 + tcol;
            const int hh = n >> 6;
            const int dk = n & (DKH - 1);
            *(short8*)&O[((size_t)(bb * NH + hh) * DKH + dk) * L_SEQ + l0] = vv;
        }
    } else {
        // Q/K: stage untransposed [m][n], then short8 stores along dk
        const float qs = (z == 0) ? QSCALE : 1.0f;
#pragma unroll
        for (int mt = 0; mt < 4; ++mt) {
            const int row0 = wm + mt * 16 + q * 4;
#pragma unroll
            for (int nt = 0; nt < 4; ++nt) {
                const int col = wn + nt * 16 + ml;
#pragma unroll
                for (int r = 0; r < 4; ++r)
                    Ts[(row0 + r) * 128 + col] = f2bf(acc[mt][nt][r] * qs);
            }
        }
        __syncthreads();
        const int mloc = t >> 3;              // 0..31 (+32*pass)
        const int c0   = t & 7;               // chunk 0..7 (+8*half)
#pragma unroll
        for (int pass = 0; pass < 4; ++pass) {
#pragma unroll
            for (int half = 0; half < 2; ++half) {
                const int m = mloc + 32 * pass;
                const int c = c0 + 8 * half;
                short8 v = *(const short8*)&Ts[m * 128 + c * 8];
                const int row = m0 + m;
                const int bb  = row >> 11;
                const int l   = row & (L_SEQ - 1);
                const int n   = n0 + c * 8;
                const int hh  = n >> 6;
                const int dk  = n & (DKH - 1);
                *(short8*)&O[(((size_t)(bb * NH + hh) * L_SEQ + l) << 6) + dk] = v;
            }
        }
    }
}

// ---------------------------------------------------------------------------
// Output GEMM (r6 K-loop) + XCD-pinned 1D grid: 8 n-tiles of one m-panel
// co-resident per XCD (m-panel 128 KB reused from L2).
// ---------------------------------------------------------------------------
__global__ __launch_bounds__(256)
void gemm_out(const unsigned short* __restrict__ OB,
              const unsigned short* __restrict__ Wt,
              float* __restrict__ out)
{
    __shared__ __align__(16) unsigned short As[2][2048];
    __shared__ __align__(16) unsigned short Bs[2][4096];

    const int t    = threadIdx.x;
    const int w    = t >> 6;
    const int lane = t & 63;

    // 512 blocks: xcd = bid&7; 8 m-tiles per XCD x 8 n-tiles
    const int bid = blockIdx.x;
    const int xcd = bid & 7;
    const int idx = bid >> 3;             // 0..63
    const int n0  = (idx & 7) * 128;
    const int m0  = (xcd * 8 + (idx >> 3)) * 64;

    const int srow = lane >> 2;
    const int sc4  = (lane & 3) ^ (srow & 3);

    const unsigned short* ag =
        OB + (size_t)(m0 + w * 16 + srow) * DMODEL + sc4 * 8;
    const unsigned short* bg[2];
    int lbo[2];
#pragma unroll
    for (int g = 0; g < 2; ++g) {
        const int R = w * 32 + g * 16;
        bg[g] = Wt + (size_t)(n0 + R + srow) * DMODEL + sc4 * 8;
        lbo[g] = R * 32;
    }
    const int lao = (w * 16) * 32;

    const int ml = lane & 15;
    const int q  = lane >> 4;
    const int wm = (w >> 1) * 32;
    const int wn = (w & 1) * 64;

    const f32x4 z4 = {0.f, 0.f, 0.f, 0.f};
    f32x4 acc[2][4];
#pragma unroll
    for (int i = 0; i < 2; ++i)
#pragma unroll
        for (int j = 0; j < 4; ++j) acc[i][j] = z4;

    gll16(ag, &As[0][lao]);
#pragma unroll
    for (int g = 0; g < 2; ++g) gll16(bg[g], &Bs[0][lbo[g]]);

    for (int j = 0; j < 32; ++j) {
        const int cur = j & 1;
        __syncthreads();
        if (j < 31) {
            const int kt = (j + 1) * 32;
            gll16(ag + kt, &As[cur ^ 1][lao]);
#pragma unroll
            for (int g = 0; g < 2; ++g)
                gll16(bg[g] + kt, &Bs[cur ^ 1][lbo[g]]);
        }
        short8 av[2], bv[4];
#pragma unroll
        for (int mt = 0; mt < 2; ++mt)
            av[mt] = *(const short8*)
                &As[cur][(wm + mt * 16 + ml) * 32 + ((q ^ (ml & 3)) * 8)];
#pragma unroll
        for (int nt = 0; nt < 4; ++nt)
            bv[nt] = *(const short8*)
                &Bs[cur][(wn + nt * 16 + ml) * 32 + ((q ^ (ml & 3)) * 8)];
#pragma unroll
        for (int mt = 0; mt < 2; ++mt)
#pragma unroll
            for (int nt = 0; nt < 4; ++nt)
                acc[mt][nt] = __builtin_amdgcn_mfma_f32_16x16x32_bf16(
                    av[mt], bv[nt], acc[mt][nt], 0, 0, 0);
    }

#pragma unroll
    for (int mt = 0; mt < 2; ++mt) {
        const int gr0 = m0 + wm + mt * 16 + q * 4;
#pragma unroll
        for (int nt = 0; nt < 4; ++nt) {
            const int col = n0 + wn + nt * 16 + ml;
#pragma unroll
            for (int r = 0; r < 4; ++r)
                out[(size_t)(gr0 + r) * DMODEL + col] = acc[mt][nt][r];
        }
    }
}

// ---------------------------------------------------------------------------
// MFMA flash attention — ROUND-5 VERSION VERBATIM (best measured: 71.7 us,
// conflicts 2.1e6). Single-buffered K/V, Q via LDS, mask via MskL prefetch,
// p = exp2(s*bit) with Q pre-scaled, XCD-pinned (b,h).
// ---------------------------------------------------------------------------
__global__ __launch_bounds__(256, 4)
void attn_mfma(const unsigned short* __restrict__ Qb,
               const unsigned short* __restrict__ Kb,
               const unsigned short* __restrict__ Vtb,
               const unsigned long long* __restrict__ MWT,
               unsigned short* __restrict__ OB)
{
    __shared__ __align__(16) unsigned short Qs[64 * 64];
    __shared__ __align__(16) unsigned short Ks[64 * 64];
    __shared__ __align__(16) unsigned short Vts[64 * 64];
    __shared__ __align__(16) unsigned short Ps[4][16 * 64];
    __shared__ __align__(16) unsigned long long MskL[64];

    const int t    = threadIdx.x;
    const int w    = t >> 6;
    const int lane = t & 63;
    const int ml   = lane & 15;
    const int quad = lane >> 4;

    const int bid = blockIdx.x;
    const int p   = (bid >> 8) * 8 + (bid & 7);
    const int jq  = (bid >> 3) & 31;
    const int h   = p & 15;
    const int b   = p >> 4;
    const int q0  = jq * 64;

    const size_t hoff = (size_t)(b * NH + h) * L_SEQ * DKH;
    const unsigned short* Qh  = Qb  + hoff;
    const unsigned short* Kh  = Kb  + hoff;
    const unsigned short* Vth = Vtb + hoff;     // [64][L_SEQ]

    const int srow = lane >> 3;
    const int sc   = (lane & 7) ^ srow;

    gll16(Qh + (size_t)(q0 + w * 16 + srow) * DKH + sc * 8, &Qs[(w * 16) * 64]);
    gll16(Qh + (size_t)(q0 + w * 16 + 8 + srow) * DKH + sc * 8, &Qs[(w * 16 + 8) * 64]);
    __syncthreads();

    short8 qf[2];
#pragma unroll
    for (int s = 0; s < 2; ++s)
        qf[s] = *(const short8*)
            &Qs[(w * 16 + ml) * 64 + (((s * 4 + quad) ^ (ml & 7)) * 8)];

    const unsigned short* kg0 = Kh + (size_t)(w * 16 + srow) * DKH + sc * 8;
    const unsigned short* kg1 = Kh + (size_t)(w * 16 + 8 + srow) * DKH + sc * 8;
    const unsigned short* vg0 = Vth + (size_t)(w * 16 + srow) * L_SEQ + sc * 8;
    const unsigned short* vg1 = Vth + (size_t)(w * 16 + 8 + srow) * L_SEQ + sc * 8;
    unsigned short* lk0 = &Ks[(w * 16) * 64];
    unsigned short* lk1 = &Ks[(w * 16 + 8) * 64];
    unsigned short* lv0 = &Vts[(w * 16) * 64];
    unsigned short* lv1 = &Vts[(w * 16 + 8) * 64];

    const unsigned long long* mg = MWT + (size_t)b * 32 * L_SEQ + q0 + t;
    unsigned long long m_pf = 0;
    if (t < 64) m_pf = mg[0];

    f32x4 oacc[4];
    const f32x4 z4 = {0.f, 0.f, 0.f, 0.f};
#pragma unroll
    for (int dt = 0; dt < 4; ++dt) oacc[dt] = z4;
    float l_i = 0.f;

    for (int j = 0; j < 32; ++j) {
        __syncthreads();
        gll16(kg0, lk0);  gll16(kg1, lk1);
        gll16(vg0, lv0);  gll16(vg1, lv1);
        kg0 += 64 * DKH;  kg1 += 64 * DKH;
        vg0 += 64;        vg1 += 64;
        if (t < 64) {
            MskL[t] = m_pf;
            if (j < 31) m_pf = mg[(size_t)(j + 1) * L_SEQ];
        }
        __syncthreads();

        f32x4 sacc[4];
#pragma unroll
        for (int kt = 0; kt < 4; ++kt) sacc[kt] = z4;
#pragma unroll
        for (int s = 0; s < 2; ++s) {
            short8 kf[4];
#pragma unroll
            for (int kt = 0; kt < 4; ++kt)
                kf[kt] = *(const short8*)
                    &Ks[(kt * 16 + ml) * 64 + (((s * 4 + quad) ^ (ml & 7)) * 8)];
#pragma unroll
            for (int kt = 0; kt < 4; ++kt)
                sacc[kt] = __builtin_amdgcn_mfma_f32_16x16x32_bf16(
                    kf[kt], qf[s], sacc[kt], 0, 0, 0);
        }

        const unsigned long long wq = MskL[w * 16 + ml] >> (quad * 4);
        const unsigned mlo = (unsigned)wq;
        const unsigned mhi = (unsigned)(wq >> 32);
        float rs = 0.f;
        float pr[4][4];
#pragma unroll
        for (int kt = 0; kt < 4; ++kt) {
            const unsigned word = (kt < 2) ? mlo : mhi;
            const int base = (kt & 1) * 16;
#pragma unroll
            for (int r = 0; r < 4; ++r) {
                const float mf = (float)((word >> (base + r)) & 1u);
                const float e  = fexp2(sacc[kt][r] * mf);
                pr[kt][r] = e;
                rs += e;
            }
        }
        rs += __shfl_xor(rs, 16);
        rs += __shfl_xor(rs, 32);
        l_i += rs;
#pragma unroll
        for (int kt = 0; kt < 4; ++kt) {
            uint2 pk;
            pk.x = pk_bf16(pr[kt][0], pr[kt][1]);
            pk.y = pk_bf16(pr[kt][2], pr[kt][3]);
            const int cp = (kt * 2 + (quad >> 1)) ^ (ml & 7);
            *(uint2*)&Ps[w][ml * 64 + cp * 8 + (quad & 1) * 4] = pk;
        }

#pragma unroll
        for (int s = 0; s < 2; ++s) {
            const short8 pf = *(const short8*)
                &Ps[w][ml * 64 + (((s * 4 + quad) ^ (ml & 7)) * 8)];
#pragma unroll
            for (int dt = 0; dt < 4; ++dt) {
                const short8 vf = *(const short8*)
                    &Vts[(dt * 16 + ml) * 64 + (((s * 4 + quad) ^ (ml & 7)) * 8)];
                oacc[dt] = __builtin_amdgcn_mfma_f32_16x16x32_bf16(
                    vf, pf, oacc[dt], 0, 0, 0);
            }
        }
    }

    const float inv = 1.0f / l_i;
    const int qrow = q0 + w * 16 + ml;
#pragma unroll
    for (int dt = 0; dt < 4; ++dt) {
        ushort4 o4;
        o4.x = f2bf(oacc[dt][0] * inv);
        o4.y = f2bf(oacc[dt][1] * inv);
        o4.z = f2bf(oacc[dt][2] * inv);
        o4.w = f2bf(oacc[dt][3] * inv);
        *(ushort4*)&OB[(size_t)(b * L_SEQ + qrow) * DMODEL + h * DKH +
                       dt * 16 + quad * 4] = o4;
    }
}

// ---------------------------------------------------------------------------
extern "C" void kernel_launch(void* const* d_in, const int* in_sizes, int n_in,
                              void* d_out, int out_size, void* d_ws, size_t ws_size,
                              hipStream_t stream)
{
    (void)in_sizes; (void)n_in; (void)out_size; (void)ws_size;

    const float* Xq   = (const float*)d_in[0];
    const float* Xk   = (const float*)d_in[1];
    const float* Xv   = (const float*)d_in[2];
    const float* Wq   = (const float*)d_in[3];
    const float* Wk   = (const float*)d_in[4];
    const float* Wv   = (const float*)d_in[5];
    const float* Wo   = (const float*)d_in[6];
    const int*   mask = (const int*)d_in[7];
    float* out = (float*)d_out;

    char* base = (char*)d_ws;
    unsigned short*     XB  = (unsigned short*)base;                 // 24 MB
    unsigned short*     WtB = (unsigned short*)(base + (24u << 20)); //  8 MB
    unsigned short*     QKV = (unsigned short*)(base + (32u << 20)); // 24 MB
    unsigned short*     OB  = (unsigned short*)(base + (56u << 20)); //  8 MB
    unsigned long long* MWT = (unsigned long long*)(base + (64u << 20)); // 1 MB

    const size_t tsz = (size_t)MROWS * DMODEL;   // 4,194,304

    prep<<<dim3(49152), 256, 0, stream>>>(
        Xq, Xk, Xv, Wq, Wk, Wv, Wo, mask, XB, WtB, MWT);

    gemm_qkv<<<dim3(768), 256, 0, stream>>>(XB, WtB, QKV);

    attn_mfma<<<dim3(1024), 256, 0, stream>>>(
        QKV, QKV + tsz, QKV + 2 * tsz, MWT, OB);

    gemm_out<<<dim3(512), 256, 0, stream>>>(OB, WtB + 3 * (size_t)DD, out);
}